// Round 12
// baseline (368.088 us; speedup 1.0000x reference)
//
#include <hip/hip_runtime.h>
#include <cstdint>
#include <cstddef>

typedef __bf16 bf16;
typedef __bf16 bf16x8 __attribute__((ext_vector_type(8)));
typedef float f32x4 __attribute__((ext_vector_type(4)));
typedef short short4v __attribute__((ext_vector_type(4)));

#define GLB_AS(p) ((const __attribute__((address_space(1))) unsigned*)(unsigned long long)(p))
#define LDS_AS(p) ((__attribute__((address_space(3))) unsigned*)(unsigned)(unsigned long long)(p))

__device__ __forceinline__ void g2l16(const void* g, void* l) {
  __builtin_amdgcn_global_load_lds(GLB_AS(g), LDS_AS(l), 16, 0, 0);
}

__device__ __forceinline__ short f2bf(float x) {
  bf16 h = (bf16)x;
  return __builtin_bit_cast(short, h);
}

// single v_exp_f32 via the compiler-visible OCML native intrinsic.
// r10 lesson: raw inline-asm v_exp_f32 bypasses the backend's TRANS-use
// hazard recognizer -> NaN. This lowers to llvm.amdgcn.exp2 with hazards ok.
extern "C" __device__ __attribute__((const)) float __ocml_native_exp2_f32(float);
__device__ __forceinline__ float fast_exp2(float x) {
  return __ocml_native_exp2_f32(x);
}

constexpr int MROWS = 4096;            // M (= B*L) for every GEMM in this block
constexpr size_t ATILE = (size_t)MROWS * 32;  // elems per k-tile of an A operand

// q pre-scale: (1/sqrt(64)) * log2(e) -> softmax runs in exp2 domain
#define QSCALE 0.18033688011112042f

// ---------------- weight transpose + cast to K-tiled ----------------
// in: fp32 [K,N] row-major; out: bf16 tiled [K/32][N][32]
__global__ __launch_bounds__(256) void transpose_tile_f32_bf16(
    const float* __restrict__ in, bf16* __restrict__ out, int K, int N)
{
  __shared__ float tile[32][33];
  int n0 = blockIdx.x * 32, k0 = blockIdx.y * 32;
  for (int i = threadIdx.y; i < 32; i += 8)
    tile[i][threadIdx.x] = in[(size_t)(k0 + i) * N + n0 + threadIdx.x];
  __syncthreads();
  bf16* obase = out + (size_t)(k0 >> 5) * N * 32;
  for (int i = threadIdx.y; i < 32; i += 8)
    obase[(size_t)(n0 + i) * 32 + threadIdx.x] = (bf16)tile[threadIdx.x][i];
}

// ---------------- layernorm: fp32 [4096,1024] -> bf16 K-tiled ----------------
__global__ __launch_bounds__(256) void ln_kernel(
    const float* __restrict__ x, const float* __restrict__ sc,
    const float* __restrict__ bi, bf16* __restrict__ out)
{
  __shared__ float wsum[4], wsq[4];
  int row = blockIdx.x;
  const float* xr = x + (size_t)row * 1024;
  int c = threadIdx.x * 4;
  float4 xv = *(const float4*)(xr + c);
  float s = xv.x + xv.y + xv.z + xv.w;
  float q = xv.x * xv.x + xv.y * xv.y + xv.z * xv.z + xv.w * xv.w;
#pragma unroll
  for (int off = 1; off < 64; off <<= 1) {
    s += __shfl_xor(s, off);
    q += __shfl_xor(q, off);
  }
  int wv = threadIdx.x >> 6;
  if ((threadIdx.x & 63) == 0) { wsum[wv] = s; wsq[wv] = q; }
  __syncthreads();
  s = wsum[0] + wsum[1] + wsum[2] + wsum[3];
  q = wsq[0] + wsq[1] + wsq[2] + wsq[3];
  float mean = s * (1.f / 1024.f);
  float var = q * (1.f / 1024.f) - mean * mean;
  float rstd = rsqrtf(var + 1e-6f);
  float4 scv = *(const float4*)(sc + c);
  float4 biv = *(const float4*)(bi + c);
  bf16* o = out + (size_t)(c >> 5) * ATILE + (size_t)row * 32 + (c & 31);
  o[0] = (bf16)((xv.x - mean) * rstd * scv.x + biv.x);
  o[1] = (bf16)((xv.y - mean) * rstd * scv.y + biv.y);
  o[2] = (bf16)((xv.z - mean) * rstd * scv.z + biv.z);
  o[3] = (bf16)((xv.w - mean) * rstd * scv.w + biv.w);
}

// ---------------- GEMM on K-tiled operands ----------------
// A: bf16 [K/32][4096][32], B: bf16 [K/32][N][32].  C[M,N] = A @ B^T.
// KTc = k-tiles per chunk; blockIdx.z = split-K chunk (EPI 3 accumulates
// into outf via fp32 atomicAdd; outf pre-seeded with the residual x1).
template <int MT, int NT, int EPI>
__global__ __launch_bounds__(256) void gemm_tt(
    const bf16* __restrict__ A, const bf16* __restrict__ Bt,
    int N, int K, int KTc,
    const float* __restrict__ bias, const float* __restrict__ resid,
    float* __restrict__ outf, bf16* __restrict__ ob0,
    bf16* __restrict__ ob1, bf16* __restrict__ ob2)
{
  constexpr int TM = MT * 32, TN = NT * 32;
  __shared__ __align__(16) bf16 As[2][TM * 32];
  __shared__ __align__(16) bf16 Bs[2][TN * 32];
  const int tid = threadIdx.x, lane = tid & 63, wave = tid >> 6;
  const int wm = wave >> 1, wn = wave & 1;
  const int quad = lane >> 4, l16 = lane & 15;
  const int kz = blockIdx.z;
  const int kt0 = kz * KTc;

  int flat = blockIdx.x + gridDim.x * blockIdx.y;
  int xcd = flat & 7, rr = flat >> 3;
  int npx = gridDim.x >> 3;
  int bn = xcd * npx + (rr % npx);
  int bm = rr / npx;

  const size_t astride = ATILE;
  const size_t bstride = (size_t)N * 32;
  const bf16* Abase = A + (size_t)bm * TM * 32 + (size_t)lane * 8;
  const bf16* Bbase = Bt + (size_t)bn * TN * 32 + (size_t)lane * 8;

  f32x4 acc[MT][NT] = {};

  auto stage = [&](int buf, int kt) {
    const bf16* Ab = Abase + (size_t)(kt0 + kt) * astride;
    const bf16* Bb = Bbase + (size_t)(kt0 + kt) * bstride;
#pragma unroll
    for (int i = 0; i < MT / 2; i++)
      g2l16(Ab + (wave + 4 * i) * 512, &As[buf][(wave + 4 * i) * 512]);
#pragma unroll
    for (int i = 0; i < NT / 2; i++)
      g2l16(Bb + (wave + 4 * i) * 512, &Bs[buf][(wave + 4 * i) * 512]);
  };

  stage(0, 0);
  int buf = 0;
  for (int kt = 0; kt < KTc; kt++) {
    __syncthreads();
    if (kt + 1 < KTc) stage(buf ^ 1, kt + 1);
    bf16x8 af[MT], bfr[NT];
#pragma unroll
    for (int mt = 0; mt < MT; mt++)
      af[mt] = *(const bf16x8*)&As[buf][(wm * MT * 16 + mt * 16 + l16) * 32 + quad * 8];
#pragma unroll
    for (int nt = 0; nt < NT; nt++)
      bfr[nt] = *(const bf16x8*)&Bs[buf][(wn * NT * 16 + nt * 16 + l16) * 32 + quad * 8];
#pragma unroll
    for (int mt = 0; mt < MT; mt++)
#pragma unroll
      for (int nt = 0; nt < NT; nt++)
        acc[mt][nt] = __builtin_amdgcn_mfma_f32_16x16x32_bf16(af[mt], bfr[nt], acc[mt][nt], 0, 0, 0);
    buf ^= 1;
  }

#pragma unroll
  for (int mt = 0; mt < MT; mt++) {
#pragma unroll
    for (int nt = 0; nt < NT; nt++) {
      int row0 = bm * TM + wm * MT * 16 + mt * 16 + quad * 4;
      int col = bn * TN + wn * NT * 16 + nt * 16 + l16;
      if (EPI == 0) {
        int b = row0 >> 11, l = row0 & 2047;
        int which = col >> 10, d = col & 1023;
        int hh = d >> 6, hdi = d & 63;
        size_t bh = (size_t)(b * 16 + hh);
        if (which == 0) {
#pragma unroll
          for (int r = 0; r < 4; r++)
            ob0[(bh * 2048 + l + r) * 64 + hdi] = (bf16)(acc[mt][nt][r] * QSCALE);
        } else if (which == 1) {
#pragma unroll
          for (int r = 0; r < 4; r++)
            ob1[(bh * 2048 + l + r) * 64 + hdi] = (bf16)acc[mt][nt][r];
        } else {
          short4v v4;
#pragma unroll
          for (int r = 0; r < 4; r++) v4[r] = f2bf(acc[mt][nt][r]);
          *(short4v*)&ob2[(bh * 64 + hdi) * 2048 + l] = v4;
        }
      } else {
#pragma unroll
        for (int r = 0; r < 4; r++) {
          int row = row0 + r;
          float v = acc[mt][nt][r];
          if (EPI == 1) {
            size_t idx = (size_t)row * N + col;
            outf[idx] = v + bias[col] + resid[idx];
          } else if (EPI == 2) {
            float t = v + bias[col];
            float u = t + 0.044715f * t * t * t;
            float g = 0.5f * t * (1.f + tanhf(0.7978845608028654f * u));
            ob0[(size_t)(col >> 5) * ATILE + (size_t)row * 32 + (col & 31)] = (bf16)g;
          } else {
            // split-K accumulate: outf pre-holds x1; chunk 0 adds bias
            size_t idx = (size_t)row * N + col;
            float add = v;
            if (kz == 0) add += bias[col];
            atomicAdd(&outf[idx], add);
          }
        }
      }
    }
  }
}

// ---------------- flash attention v9 (no-max softmax + native exp2) --------
// Q,K: bf16 [BH,2048,64] (q pre-scaled by QSCALE -> exp2 domain).
// V: bf16 [BH,64,2048] (V^T).
// 256 thr / 4 waves, Q-tile 128 (32 rows/wave as 2x16), K-tile 128.
__global__ __launch_bounds__(256, 2) void flash_attn(
    const bf16* __restrict__ Q, const bf16* __restrict__ Kg,
    const bf16* __restrict__ Vg, bf16* __restrict__ O)
{
  __shared__ __align__(16) bf16 Ks[128 * 72];   // [kpos][hd], padded
  __shared__ __align__(16) bf16 Vs[64 * 136];   // [hd][kpos], padded
  const int tid = threadIdx.x, lane = tid & 63, wave = tid >> 6;
  const int quad = lane >> 4, l16 = lane & 15;
  const int qt = blockIdx.x, bh = blockIdx.y;
  const int b = bh >> 4, h = bh & 15;

  const bf16* qg = Q + ((size_t)bh * 2048 + qt * 128) * 64;
  const bf16* kg = Kg + (size_t)bh * 2048 * 64;
  const bf16* vg = Vg + (size_t)bh * 64 * 2048;

  bf16x8 qf[2][2];
#pragma unroll
  for (int s = 0; s < 2; s++)
#pragma unroll
    for (int kk = 0; kk < 2; kk++)
      qf[s][kk] = *(const bf16x8*)&qg[(size_t)(wave * 32 + s * 16 + l16) * 64 + kk * 32 + quad * 8];

  f32x4 oacc[2][4] = {};
  float lrow[2] = {0.f, 0.f};

  for (int kt = 0; kt < 16; kt++) {
    __syncthreads();
#pragma unroll
    for (int i = 0; i < 4; i++) {
      int t = tid + i * 256;
      *(bf16x8*)&Ks[(t >> 3) * 72 + (t & 7) * 8] =
          *(const bf16x8*)&kg[((size_t)kt * 128 + (t >> 3)) * 64 + (t & 7) * 8];
      *(bf16x8*)&Vs[(t >> 4) * 136 + (t & 15) * 8] =
          *(const bf16x8*)&vg[(size_t)(t >> 4) * 2048 + kt * 128 + (t & 15) * 8];
    }
    __syncthreads();

    f32x4 sacc[2][8] = {};
#pragma unroll
    for (int kk = 0; kk < 2; kk++) {
#pragma unroll
      for (int ct = 0; ct < 8; ct++) {
        bf16x8 kf = *(const bf16x8*)&Ks[(ct * 16 + l16) * 72 + kk * 32 + quad * 8];
        sacc[0][ct] = __builtin_amdgcn_mfma_f32_16x16x32_bf16(kf, qf[0][kk], sacc[0][ct], 0, 0, 0);
        sacc[1][ct] = __builtin_amdgcn_mfma_f32_16x16x32_bf16(kf, qf[1][kk], sacc[1][ct], 0, 0, 0);
      }
    }

    short4v pf[2][8];
#pragma unroll
    for (int s = 0; s < 2; s++) {
      float sum = 0.f;
#pragma unroll
      for (int ct = 0; ct < 8; ct++) {
#pragma unroll
        for (int r = 0; r < 4; r++) {
          float p = fast_exp2(sacc[s][ct][r]);
          sum += p;
          pf[s][ct][r] = f2bf(p);
        }
      }
      sum += __shfl_xor(sum, 16);
      sum += __shfl_xor(sum, 32);
      lrow[s] += sum;
    }

#pragma unroll
    for (int ot = 0; ot < 4; ot++) {
#pragma unroll
      for (int ct = 0; ct < 8; ct++) {
        short4v vf = *(const short4v*)&Vs[(ot * 16 + l16) * 136 + ct * 16 + quad * 4];
        oacc[0][ot] = __builtin_amdgcn_mfma_f32_16x16x16bf16_1k(vf, pf[0][ct], oacc[0][ot], 0, 0, 0);
        oacc[1][ot] = __builtin_amdgcn_mfma_f32_16x16x16bf16_1k(vf, pf[1][ct], oacc[1][ot], 0, 0, 0);
      }
    }
  }

#pragma unroll
  for (int s = 0; s < 2; s++) {
    float inv = 1.f / lrow[s];
    int qrow = qt * 128 + wave * 32 + s * 16 + l16;
    size_t grow = (size_t)b * 2048 + qrow;
#pragma unroll
    for (int ot = 0; ot < 4; ot++) {
      int col = h * 64 + ot * 16 + quad * 4;
      short4v o4;
#pragma unroll
      for (int r = 0; r < 4; r++) o4[r] = f2bf(oacc[s][ot][r] * inv);
      *(short4v*)&O[(size_t)(col >> 5) * ATILE + grow * 32 + (col & 31)] = o4;
    }
  }
}

// ---------------- launch ----------------
extern "C" void kernel_launch(void* const* d_in, const int* in_sizes, int n_in,
                              void* d_out, int out_size, void* d_ws, size_t ws_size,
                              hipStream_t stream)
{
  const float* x     = (const float*)d_in[0];
  const float* ln1s  = (const float*)d_in[1];
  const float* ln1b  = (const float*)d_in[2];
  const float* wqkv  = (const float*)d_in[3];
  const float* wproj = (const float*)d_in[4];
  const float* bproj = (const float*)d_in[5];
  const float* ln2s  = (const float*)d_in[6];
  const float* ln2b  = (const float*)d_in[7];
  const float* wmlp1 = (const float*)d_in[8];
  const float* bmlp1 = (const float*)d_in[9];
  const float* wmlp2 = (const float*)d_in[10];
  const float* bmlp2 = (const float*)d_in[11];
  float* out = (float*)d_out;

  char* ws = (char*)d_ws;
  bf16* wqkv_t  = (bf16*)(ws + 0);          // tiled [32][3072][32]
  bf16* wproj_t = (bf16*)(ws + 6291456);    // tiled [32][1024][32]
  bf16* wmlp1_t = (bf16*)(ws + 8388608);    // tiled [32][4096][32]
  bf16* wmlp2_t = (bf16*)(ws + 16777216);   // tiled [128][1024][32]
  bf16* hbuf    = (bf16*)(ws + 25165824);   // tiled [32][4096][32]
  bf16* qb      = (bf16*)(ws + 33554432);   // [32,2048,64]
  bf16* kb      = (bf16*)(ws + 41943040);   // [32,2048,64]
  bf16* vb      = (bf16*)(ws + 50331648);   // [32,64,2048]
  bf16* aout    = (bf16*)(ws + 58720256);   // tiled [32][4096][32]
  bf16* mbuf    = (bf16*)(ws + 33554432);   // tiled [128][4096][32] aliases q/k/v/aout

  dim3 tb(32, 8);
  transpose_tile_f32_bf16<<<dim3(96, 32), tb, 0, stream>>>(wqkv, wqkv_t, 1024, 3072);
  transpose_tile_f32_bf16<<<dim3(32, 32), tb, 0, stream>>>(wproj, wproj_t, 1024, 1024);
  transpose_tile_f32_bf16<<<dim3(128, 32), tb, 0, stream>>>(wmlp1, wmlp1_t, 1024, 4096);
  transpose_tile_f32_bf16<<<dim3(32, 128), tb, 0, stream>>>(wmlp2, wmlp2_t, 4096, 1024);

  ln_kernel<<<4096, 256, 0, stream>>>(x, ln1s, ln1b, hbuf);
  gemm_tt<4, 4, 0><<<dim3(24, 32, 1), 256, 0, stream>>>(hbuf, wqkv_t, 3072, 1024, 32,
                                                        nullptr, nullptr, nullptr, qb, kb, vb);
  flash_attn<<<dim3(16, 32), 256, 0, stream>>>(qb, kb, vb, aout);
  gemm_tt<2, 4, 1><<<dim3(8, 64, 1), 256, 0, stream>>>(aout, wproj_t, 1024, 1024, 32,
                                                       bproj, x, out, nullptr, nullptr, nullptr);
  ln_kernel<<<4096, 256, 0, stream>>>(out, ln2s, ln2b, hbuf);
  gemm_tt<4, 4, 2><<<dim3(32, 32, 1), 256, 0, stream>>>(hbuf, wmlp1_t, 4096, 1024, 32,
                                                        bmlp1, nullptr, nullptr, mbuf, nullptr, nullptr);
  // mlp2: 128x128 tiles, split-K=2 (KTc=64 tiles of 32), atomic accumulate
  // into out (holds x1 from proj); kz==0 contributes bias.
  gemm_tt<4, 4, 3><<<dim3(8, 32, 2), 256, 0, stream>>>(mbuf, wmlp2_t, 1024, 4096, 64,
                                                       bmlp2, nullptr, out, nullptr, nullptr, nullptr);
}

// Round 13
// 357.099 us; speedup vs baseline: 1.0308x; 1.0308x over previous
//
#include <hip/hip_runtime.h>
#include <cstdint>
#include <cstddef>

typedef __bf16 bf16;
typedef __bf16 bf16x8 __attribute__((ext_vector_type(8)));
typedef float f32x4 __attribute__((ext_vector_type(4)));
typedef short short4v __attribute__((ext_vector_type(4)));

#define GLB_AS(p) ((const __attribute__((address_space(1))) unsigned*)(unsigned long long)(p))
#define LDS_AS(p) ((__attribute__((address_space(3))) unsigned*)(unsigned)(unsigned long long)(p))

__device__ __forceinline__ void g2l16(const void* g, void* l) {
  __builtin_amdgcn_global_load_lds(GLB_AS(g), LDS_AS(l), 16, 0, 0);
}

__device__ __forceinline__ short f2bf(float x) {
  bf16 h = (bf16)x;
  return __builtin_bit_cast(short, h);
}

// single v_exp_f32 via the compiler-visible OCML native intrinsic.
// r10 lesson: raw inline-asm v_exp_f32 bypasses the backend's TRANS-use
// hazard recognizer -> NaN. This lowers to llvm.amdgcn.exp2 with hazards ok.
extern "C" __device__ __attribute__((const)) float __ocml_native_exp2_f32(float);
__device__ __forceinline__ float fast_exp2(float x) {
  return __ocml_native_exp2_f32(x);
}

constexpr int MROWS = 4096;            // M (= B*L) for every GEMM in this block
constexpr size_t ATILE = (size_t)MROWS * 32;  // elems per k-tile of an A operand

// q pre-scale: (1/sqrt(64)) * log2(e) -> softmax runs in exp2 domain
#define QSCALE 0.18033688011112042f

// ---------------- shared bodies ----------------
// transpose+cast: in fp32 [K,N] -> out bf16 tiled [K/32][N][32], one 32x32 tile
__device__ __forceinline__ void transpose_body(
    const float* __restrict__ in, bf16* __restrict__ out, int K, int N,
    int bx, int by, float (*tile)[33], int tid)
{
  int tx = tid & 31, ty = tid >> 5;           // 32 x 8
  int n0 = bx * 32, k0 = by * 32;
  for (int i = ty; i < 32; i += 8)
    tile[i][tx] = in[(size_t)(k0 + i) * N + n0 + tx];
  __syncthreads();
  bf16* obase = out + (size_t)(k0 >> 5) * N * 32;
  for (int i = ty; i < 32; i += 8)
    obase[(size_t)(n0 + i) * 32 + tx] = (bf16)tile[tx][i];
}

// layernorm row: fp32 [4096,1024] -> bf16 K-tiled [32][4096][32]
__device__ __forceinline__ void ln_body(
    const float* __restrict__ x, const float* __restrict__ sc,
    const float* __restrict__ bi, bf16* __restrict__ out,
    int row, float* wsum, float* wsq, int tid)
{
  const float* xr = x + (size_t)row * 1024;
  int c = tid * 4;
  float4 xv = *(const float4*)(xr + c);
  float s = xv.x + xv.y + xv.z + xv.w;
  float q = xv.x * xv.x + xv.y * xv.y + xv.z * xv.z + xv.w * xv.w;
#pragma unroll
  for (int off = 1; off < 64; off <<= 1) {
    s += __shfl_xor(s, off);
    q += __shfl_xor(q, off);
  }
  int wv = tid >> 6;
  if ((tid & 63) == 0) { wsum[wv] = s; wsq[wv] = q; }
  __syncthreads();
  s = wsum[0] + wsum[1] + wsum[2] + wsum[3];
  q = wsq[0] + wsq[1] + wsq[2] + wsq[3];
  float mean = s * (1.f / 1024.f);
  float var = q * (1.f / 1024.f) - mean * mean;
  float rstd = rsqrtf(var + 1e-6f);
  float4 scv = *(const float4*)(sc + c);
  float4 biv = *(const float4*)(bi + c);
  bf16* o = out + (size_t)(c >> 5) * ATILE + (size_t)row * 32 + (c & 31);
  o[0] = (bf16)((xv.x - mean) * rstd * scv.x + biv.x);
  o[1] = (bf16)((xv.y - mean) * rstd * scv.y + biv.y);
  o[2] = (bf16)((xv.z - mean) * rstd * scv.z + biv.z);
  o[3] = (bf16)((xv.w - mean) * rstd * scv.w + biv.w);
}

// ---------------- fused prologue: 4 weight transposes + ln1 ----------------
// blocks [0,3072) wqkv, [3072,4096) wproj, [4096,8192) wmlp1,
// [8192,12288) wmlp2, [12288,16384) ln1 rows. Branch is block-uniform.
__global__ __launch_bounds__(256) void prep_kernel(
    const float* __restrict__ wqkv, const float* __restrict__ wproj,
    const float* __restrict__ wmlp1, const float* __restrict__ wmlp2,
    bf16* __restrict__ wqkv_t, bf16* __restrict__ wproj_t,
    bf16* __restrict__ wmlp1_t, bf16* __restrict__ wmlp2_t,
    const float* __restrict__ x, const float* __restrict__ ln1s,
    const float* __restrict__ ln1b, bf16* __restrict__ hbuf)
{
  __shared__ float tile[32][33];
  __shared__ float wsum[4], wsq[4];
  int bid = blockIdx.x, tid = threadIdx.x;
  if (bid < 3072)
    transpose_body(wqkv, wqkv_t, 1024, 3072, bid % 96, bid / 96, tile, tid);
  else if (bid < 4096) {
    int i = bid - 3072;
    transpose_body(wproj, wproj_t, 1024, 1024, i % 32, i / 32, tile, tid);
  } else if (bid < 8192) {
    int i = bid - 4096;
    transpose_body(wmlp1, wmlp1_t, 1024, 4096, i % 128, i / 128, tile, tid);
  } else if (bid < 12288) {
    int i = bid - 8192;
    transpose_body(wmlp2, wmlp2_t, 4096, 1024, i % 32, i / 32, tile, tid);
  } else {
    ln_body(x, ln1s, ln1b, hbuf, bid - 12288, wsum, wsq, tid);
  }
}

// ---------------- standalone layernorm (ln2) ----------------
__global__ __launch_bounds__(256) void ln_kernel(
    const float* __restrict__ x, const float* __restrict__ sc,
    const float* __restrict__ bi, bf16* __restrict__ out)
{
  __shared__ float wsum[4], wsq[4];
  ln_body(x, sc, bi, out, blockIdx.x, wsum, wsq, threadIdx.x);
}

// ---------------- GEMM on K-tiled operands ----------------
// A: bf16 [K/32][4096][32], B: bf16 [K/32][N][32].  C[M,N] = A @ B^T.
// EPI 0: qkv scatter; EPI 1: outf = v + bias + resid (fp32); EPI 2: gelu->ob0.
template <int MT, int NT, int EPI>
__global__ __launch_bounds__(256) void gemm_tt(
    const bf16* __restrict__ A, const bf16* __restrict__ Bt,
    int N, int K,
    const float* __restrict__ bias, const float* __restrict__ resid,
    float* __restrict__ outf, bf16* __restrict__ ob0,
    bf16* __restrict__ ob1, bf16* __restrict__ ob2)
{
  constexpr int TM = MT * 32, TN = NT * 32;
  __shared__ __align__(16) bf16 As[2][TM * 32];
  __shared__ __align__(16) bf16 Bs[2][TN * 32];
  const int tid = threadIdx.x, lane = tid & 63, wave = tid >> 6;
  const int wm = wave >> 1, wn = wave & 1;
  const int quad = lane >> 4, l16 = lane & 15;

  int flat = blockIdx.x + gridDim.x * blockIdx.y;
  int xcd = flat & 7, rr = flat >> 3;
  int npx = gridDim.x >> 3;
  int bn = xcd * npx + (rr % npx);
  int bm = rr / npx;

  const size_t astride = ATILE;
  const size_t bstride = (size_t)N * 32;
  const bf16* Abase = A + (size_t)bm * TM * 32 + (size_t)lane * 8;
  const bf16* Bbase = Bt + (size_t)bn * TN * 32 + (size_t)lane * 8;

  f32x4 acc[MT][NT] = {};
  const int KT = K >> 5;

  auto stage = [&](int buf, int kt) {
    const bf16* Ab = Abase + (size_t)kt * astride;
    const bf16* Bb = Bbase + (size_t)kt * bstride;
#pragma unroll
    for (int i = 0; i < MT / 2; i++)
      g2l16(Ab + (wave + 4 * i) * 512, &As[buf][(wave + 4 * i) * 512]);
#pragma unroll
    for (int i = 0; i < NT / 2; i++)
      g2l16(Bb + (wave + 4 * i) * 512, &Bs[buf][(wave + 4 * i) * 512]);
  };

  stage(0, 0);
  int buf = 0;
  for (int kt = 0; kt < KT; kt++) {
    __syncthreads();
    if (kt + 1 < KT) stage(buf ^ 1, kt + 1);
    bf16x8 af[MT], bfr[NT];
#pragma unroll
    for (int mt = 0; mt < MT; mt++)
      af[mt] = *(const bf16x8*)&As[buf][(wm * MT * 16 + mt * 16 + l16) * 32 + quad * 8];
#pragma unroll
    for (int nt = 0; nt < NT; nt++)
      bfr[nt] = *(const bf16x8*)&Bs[buf][(wn * NT * 16 + nt * 16 + l16) * 32 + quad * 8];
#pragma unroll
    for (int mt = 0; mt < MT; mt++)
#pragma unroll
      for (int nt = 0; nt < NT; nt++)
        acc[mt][nt] = __builtin_amdgcn_mfma_f32_16x16x32_bf16(af[mt], bfr[nt], acc[mt][nt], 0, 0, 0);
    buf ^= 1;
  }

#pragma unroll
  for (int mt = 0; mt < MT; mt++) {
#pragma unroll
    for (int nt = 0; nt < NT; nt++) {
      int row0 = bm * TM + wm * MT * 16 + mt * 16 + quad * 4;
      int col = bn * TN + wn * NT * 16 + nt * 16 + l16;
      if (EPI == 0) {
        int b = row0 >> 11, l = row0 & 2047;
        int which = col >> 10, d = col & 1023;
        int hh = d >> 6, hdi = d & 63;
        size_t bh = (size_t)(b * 16 + hh);
        if (which == 0) {
#pragma unroll
          for (int r = 0; r < 4; r++)
            ob0[(bh * 2048 + l + r) * 64 + hdi] = (bf16)(acc[mt][nt][r] * QSCALE);
        } else if (which == 1) {
#pragma unroll
          for (int r = 0; r < 4; r++)
            ob1[(bh * 2048 + l + r) * 64 + hdi] = (bf16)acc[mt][nt][r];
        } else {
          short4v v4;
#pragma unroll
          for (int r = 0; r < 4; r++) v4[r] = f2bf(acc[mt][nt][r]);
          *(short4v*)&ob2[(bh * 64 + hdi) * 2048 + l] = v4;
        }
      } else {
#pragma unroll
        for (int r = 0; r < 4; r++) {
          int row = row0 + r;
          float v = acc[mt][nt][r];
          if (EPI == 1) {
            size_t idx = (size_t)row * N + col;
            outf[idx] = v + bias[col] + resid[idx];
          } else {
            float t = v + bias[col];
            float u = t + 0.044715f * t * t * t;
            float g = 0.5f * t * (1.f + tanhf(0.7978845608028654f * u));
            ob0[(size_t)(col >> 5) * ATILE + (size_t)row * 32 + (col & 31)] = (bf16)g;
          }
        }
      }
    }
  }
}

// ---------------- flash attention v9 (no-max softmax + native exp2) --------
// Q,K: bf16 [BH,2048,64] (q pre-scaled by QSCALE -> exp2 domain).
// V: bf16 [BH,64,2048] (V^T).
// 256 thr / 4 waves, Q-tile 128 (32 rows/wave as 2x16), K-tile 128.
__global__ __launch_bounds__(256, 2) void flash_attn(
    const bf16* __restrict__ Q, const bf16* __restrict__ Kg,
    const bf16* __restrict__ Vg, bf16* __restrict__ O)
{
  __shared__ __align__(16) bf16 Ks[128 * 72];   // [kpos][hd], padded
  __shared__ __align__(16) bf16 Vs[64 * 136];   // [hd][kpos], padded
  const int tid = threadIdx.x, lane = tid & 63, wave = tid >> 6;
  const int quad = lane >> 4, l16 = lane & 15;
  const int qt = blockIdx.x, bh = blockIdx.y;
  const int b = bh >> 4, h = bh & 15;

  const bf16* qg = Q + ((size_t)bh * 2048 + qt * 128) * 64;
  const bf16* kg = Kg + (size_t)bh * 2048 * 64;
  const bf16* vg = Vg + (size_t)bh * 64 * 2048;

  bf16x8 qf[2][2];
#pragma unroll
  for (int s = 0; s < 2; s++)
#pragma unroll
    for (int kk = 0; kk < 2; kk++)
      qf[s][kk] = *(const bf16x8*)&qg[(size_t)(wave * 32 + s * 16 + l16) * 64 + kk * 32 + quad * 8];

  f32x4 oacc[2][4] = {};
  float lrow[2] = {0.f, 0.f};

  for (int kt = 0; kt < 16; kt++) {
    __syncthreads();
#pragma unroll
    for (int i = 0; i < 4; i++) {
      int t = tid + i * 256;
      *(bf16x8*)&Ks[(t >> 3) * 72 + (t & 7) * 8] =
          *(const bf16x8*)&kg[((size_t)kt * 128 + (t >> 3)) * 64 + (t & 7) * 8];
      *(bf16x8*)&Vs[(t >> 4) * 136 + (t & 15) * 8] =
          *(const bf16x8*)&vg[(size_t)(t >> 4) * 2048 + kt * 128 + (t & 15) * 8];
    }
    __syncthreads();

    f32x4 sacc[2][8] = {};
#pragma unroll
    for (int kk = 0; kk < 2; kk++) {
#pragma unroll
      for (int ct = 0; ct < 8; ct++) {
        bf16x8 kf = *(const bf16x8*)&Ks[(ct * 16 + l16) * 72 + kk * 32 + quad * 8];
        sacc[0][ct] = __builtin_amdgcn_mfma_f32_16x16x32_bf16(kf, qf[0][kk], sacc[0][ct], 0, 0, 0);
        sacc[1][ct] = __builtin_amdgcn_mfma_f32_16x16x32_bf16(kf, qf[1][kk], sacc[1][ct], 0, 0, 0);
      }
    }

    short4v pf[2][8];
#pragma unroll
    for (int s = 0; s < 2; s++) {
      float sum = 0.f;
#pragma unroll
      for (int ct = 0; ct < 8; ct++) {
#pragma unroll
        for (int r = 0; r < 4; r++) {
          float p = fast_exp2(sacc[s][ct][r]);
          sum += p;
          pf[s][ct][r] = f2bf(p);
        }
      }
      sum += __shfl_xor(sum, 16);
      sum += __shfl_xor(sum, 32);
      lrow[s] += sum;
    }

#pragma unroll
    for (int ot = 0; ot < 4; ot++) {
#pragma unroll
      for (int ct = 0; ct < 8; ct++) {
        short4v vf = *(const short4v*)&Vs[(ot * 16 + l16) * 136 + ct * 16 + quad * 4];
        oacc[0][ot] = __builtin_amdgcn_mfma_f32_16x16x16bf16_1k(vf, pf[0][ct], oacc[0][ot], 0, 0, 0);
        oacc[1][ot] = __builtin_amdgcn_mfma_f32_16x16x16bf16_1k(vf, pf[1][ct], oacc[1][ot], 0, 0, 0);
      }
    }
  }

#pragma unroll
  for (int s = 0; s < 2; s++) {
    float inv = 1.f / lrow[s];
    int qrow = qt * 128 + wave * 32 + s * 16 + l16;
    size_t grow = (size_t)b * 2048 + qrow;
#pragma unroll
    for (int ot = 0; ot < 4; ot++) {
      int col = h * 64 + ot * 16 + quad * 4;
      short4v o4;
#pragma unroll
      for (int r = 0; r < 4; r++) o4[r] = f2bf(oacc[s][ot][r] * inv);
      *(short4v*)&O[(size_t)(col >> 5) * ATILE + grow * 32 + (col & 31)] = o4;
    }
  }
}

// ---------------- launch ----------------
extern "C" void kernel_launch(void* const* d_in, const int* in_sizes, int n_in,
                              void* d_out, int out_size, void* d_ws, size_t ws_size,
                              hipStream_t stream)
{
  const float* x     = (const float*)d_in[0];
  const float* ln1s  = (const float*)d_in[1];
  const float* ln1b  = (const float*)d_in[2];
  const float* wqkv  = (const float*)d_in[3];
  const float* wproj = (const float*)d_in[4];
  const float* bproj = (const float*)d_in[5];
  const float* ln2s  = (const float*)d_in[6];
  const float* ln2b  = (const float*)d_in[7];
  const float* wmlp1 = (const float*)d_in[8];
  const float* bmlp1 = (const float*)d_in[9];
  const float* wmlp2 = (const float*)d_in[10];
  const float* bmlp2 = (const float*)d_in[11];
  float* out = (float*)d_out;

  char* ws = (char*)d_ws;
  bf16* wqkv_t  = (bf16*)(ws + 0);          // tiled [32][3072][32]
  bf16* wproj_t = (bf16*)(ws + 6291456);    // tiled [32][1024][32]
  bf16* wmlp1_t = (bf16*)(ws + 8388608);    // tiled [32][4096][32]
  bf16* wmlp2_t = (bf16*)(ws + 16777216);   // tiled [128][1024][32]
  bf16* hbuf    = (bf16*)(ws + 25165824);   // tiled [32][4096][32]
  bf16* qb      = (bf16*)(ws + 33554432);   // [32,2048,64]
  bf16* kb      = (bf16*)(ws + 41943040);   // [32,2048,64]
  bf16* vb      = (bf16*)(ws + 50331648);   // [32,64,2048]
  bf16* aout    = (bf16*)(ws + 58720256);   // tiled [32][4096][32]
  bf16* mbuf    = (bf16*)(ws + 33554432);   // tiled [128][4096][32] aliases q/k/v/aout

  // fused prologue: all 4 weight transposes + ln1 (11 -> 7 launches total)
  prep_kernel<<<16384, 256, 0, stream>>>(wqkv, wproj, wmlp1, wmlp2,
                                         wqkv_t, wproj_t, wmlp1_t, wmlp2_t,
                                         x, ln1s, ln1b, hbuf);
  gemm_tt<4, 4, 0><<<dim3(24, 32), 256, 0, stream>>>(hbuf, wqkv_t, 3072, 1024,
                                                     nullptr, nullptr, nullptr, qb, kb, vb);
  flash_attn<<<dim3(16, 32), 256, 0, stream>>>(qb, kb, vb, aout);
  gemm_tt<2, 4, 1><<<dim3(8, 64), 256, 0, stream>>>(aout, wproj_t, 1024, 1024,
                                                    bproj, x, out, nullptr, nullptr, nullptr);
  ln_kernel<<<4096, 256, 0, stream>>>(out, ln2s, ln2b, hbuf);
  gemm_tt<4, 4, 2><<<dim3(32, 32), 256, 0, stream>>>(hbuf, wmlp1_t, 4096, 1024,
                                                     bmlp1, nullptr, nullptr, mbuf, nullptr, nullptr);
  // mlp2: r11 config (known 61.4 us) -- direct store v + bias + resid(out)
  gemm_tt<2, 4, 1><<<dim3(8, 64), 256, 0, stream>>>(mbuf, wmlp2_t, 1024, 4096,
                                                    bmlp2, out, out, nullptr, nullptr, nullptr);
}

// Round 15
// 340.892 us; speedup vs baseline: 1.0798x; 1.0475x over previous
//
#include <hip/hip_runtime.h>
#include <hip/hip_bf16.h>
#include <cstdint>
#include <cstddef>

typedef __bf16 bf16;
typedef __bf16 bf16x8 __attribute__((ext_vector_type(8)));
typedef float f32x4 __attribute__((ext_vector_type(4)));
typedef short short4v __attribute__((ext_vector_type(4)));
typedef unsigned uint2v __attribute__((ext_vector_type(2)));

#define GLB_AS(p) ((const __attribute__((address_space(1))) unsigned*)(unsigned long long)(p))
#define LDS_AS(p) ((__attribute__((address_space(3))) unsigned*)(unsigned)(unsigned long long)(p))

__device__ __forceinline__ void g2l16(const void* g, void* l) {
  __builtin_amdgcn_global_load_lds(GLB_AS(g), LDS_AS(l), 16, 0, 0);
}

__device__ __forceinline__ short f2bf(float x) {
  bf16 h = (bf16)x;
  return __builtin_bit_cast(short, h);
}

// packed f32x2 -> bf16x2 convert; memcpy because __hip_bfloat162 is not
// trivially copyable (r14 compile lesson).
__device__ __forceinline__ unsigned pk_bf16(float a, float b) {
  __hip_bfloat162 h = __float22bfloat162_rn(float2{a, b});
  unsigned u;
  __builtin_memcpy(&u, &h, 4);
  return u;
}

// native transcendentals via compiler-visible OCML intrinsics.
// r10 lesson: raw inline-asm v_exp_f32 bypasses the TRANS-use hazard
// recognizer -> NaN. These lower to llvm.amdgcn.{exp2,rcp} with hazards ok.
extern "C" __device__ __attribute__((const)) float __ocml_native_exp2_f32(float);
extern "C" __device__ __attribute__((const)) float __ocml_native_recip_f32(float);
__device__ __forceinline__ float fast_exp2(float x) {
  return __ocml_native_exp2_f32(x);
}
// tanh(a) = 1 - 2/(e^{2a}+1); e^{2a} = 2^{2a*log2(e)}. ~8 VALU vs libm ~40.
__device__ __forceinline__ float fast_tanh(float a) {
  float e = __ocml_native_exp2_f32(a * 2.8853900817779268f);
  return 1.f - 2.f * __ocml_native_recip_f32(e + 1.f);
}

constexpr int MROWS = 4096;            // M (= B*L) for every GEMM in this block
constexpr size_t ATILE = (size_t)MROWS * 32;  // elems per k-tile of an A operand

// q pre-scale: (1/sqrt(64)) * log2(e) -> softmax runs in exp2 domain
#define QSCALE 0.18033688011112042f

// ---------------- shared bodies ----------------
__device__ __forceinline__ void transpose_body(
    const float* __restrict__ in, bf16* __restrict__ out, int K, int N,
    int bx, int by, float (*tile)[33], int tid)
{
  int tx = tid & 31, ty = tid >> 5;           // 32 x 8
  int n0 = bx * 32, k0 = by * 32;
  for (int i = ty; i < 32; i += 8)
    tile[i][tx] = in[(size_t)(k0 + i) * N + n0 + tx];
  __syncthreads();
  bf16* obase = out + (size_t)(k0 >> 5) * N * 32;
  for (int i = ty; i < 32; i += 8)
    obase[(size_t)(n0 + i) * 32 + tx] = (bf16)tile[tx][i];
}

__device__ __forceinline__ void ln_body(
    const float* __restrict__ x, const float* __restrict__ sc,
    const float* __restrict__ bi, bf16* __restrict__ out,
    int row, float* wsum, float* wsq, int tid)
{
  const float* xr = x + (size_t)row * 1024;
  int c = tid * 4;
  float4 xv = *(const float4*)(xr + c);
  float s = xv.x + xv.y + xv.z + xv.w;
  float q = xv.x * xv.x + xv.y * xv.y + xv.z * xv.z + xv.w * xv.w;
#pragma unroll
  for (int off = 1; off < 64; off <<= 1) {
    s += __shfl_xor(s, off);
    q += __shfl_xor(q, off);
  }
  int wv = tid >> 6;
  if ((tid & 63) == 0) { wsum[wv] = s; wsq[wv] = q; }
  __syncthreads();
  s = wsum[0] + wsum[1] + wsum[2] + wsum[3];
  q = wsq[0] + wsq[1] + wsq[2] + wsq[3];
  float mean = s * (1.f / 1024.f);
  float var = q * (1.f / 1024.f) - mean * mean;
  float rstd = rsqrtf(var + 1e-6f);
  float4 scv = *(const float4*)(sc + c);
  float4 biv = *(const float4*)(bi + c);
  bf16* o = out + (size_t)(c >> 5) * ATILE + (size_t)row * 32 + (c & 31);
  o[0] = (bf16)((xv.x - mean) * rstd * scv.x + biv.x);
  o[1] = (bf16)((xv.y - mean) * rstd * scv.y + biv.y);
  o[2] = (bf16)((xv.z - mean) * rstd * scv.z + biv.z);
  o[3] = (bf16)((xv.w - mean) * rstd * scv.w + biv.w);
}

// ---------------- fused prologue: 4 weight transposes + ln1 ----------------
__global__ __launch_bounds__(256) void prep_kernel(
    const float* __restrict__ wqkv, const float* __restrict__ wproj,
    const float* __restrict__ wmlp1, const float* __restrict__ wmlp2,
    bf16* __restrict__ wqkv_t, bf16* __restrict__ wproj_t,
    bf16* __restrict__ wmlp1_t, bf16* __restrict__ wmlp2_t,
    const float* __restrict__ x, const float* __restrict__ ln1s,
    const float* __restrict__ ln1b, bf16* __restrict__ hbuf)
{
  __shared__ float tile[32][33];
  __shared__ float wsum[4], wsq[4];
  int bid = blockIdx.x, tid = threadIdx.x;
  if (bid < 3072)
    transpose_body(wqkv, wqkv_t, 1024, 3072, bid % 96, bid / 96, tile, tid);
  else if (bid < 4096) {
    int i = bid - 3072;
    transpose_body(wproj, wproj_t, 1024, 1024, i % 32, i / 32, tile, tid);
  } else if (bid < 8192) {
    int i = bid - 4096;
    transpose_body(wmlp1, wmlp1_t, 1024, 4096, i % 128, i / 128, tile, tid);
  } else if (bid < 12288) {
    int i = bid - 8192;
    transpose_body(wmlp2, wmlp2_t, 4096, 1024, i % 32, i / 32, tile, tid);
  } else {
    ln_body(x, ln1s, ln1b, hbuf, bid - 12288, wsum, wsq, tid);
  }
}

// ---------------- standalone layernorm (ln2) ----------------
__global__ __launch_bounds__(256) void ln_kernel(
    const float* __restrict__ x, const float* __restrict__ sc,
    const float* __restrict__ bi, bf16* __restrict__ out)
{
  __shared__ float wsum[4], wsq[4];
  ln_body(x, sc, bi, out, blockIdx.x, wsum, wsq, threadIdx.x);
}

// ---------------- GEMM on K-tiled operands ----------------
// A: bf16 [K/32][4096][32], B: bf16 [K/32][N][32].  C[M,N] = A @ B^T.
// EPI 0: qkv scatter; EPI 1: outf = v + bias + resid (fp32); EPI 2: gelu->ob0.
template <int MT, int NT, int EPI>
__global__ __launch_bounds__(256) void gemm_tt(
    const bf16* __restrict__ A, const bf16* __restrict__ Bt,
    int N, int K,
    const float* __restrict__ bias, const float* __restrict__ resid,
    float* __restrict__ outf, bf16* __restrict__ ob0,
    bf16* __restrict__ ob1, bf16* __restrict__ ob2)
{
  constexpr int TM = MT * 32, TN = NT * 32;
  __shared__ __align__(16) bf16 As[2][TM * 32];
  __shared__ __align__(16) bf16 Bs[2][TN * 32];
  const int tid = threadIdx.x, lane = tid & 63, wave = tid >> 6;
  const int wm = wave >> 1, wn = wave & 1;
  const int quad = lane >> 4, l16 = lane & 15;

  int flat = blockIdx.x + gridDim.x * blockIdx.y;
  int xcd = flat & 7, rr = flat >> 3;
  int npx = gridDim.x >> 3;
  int bn = xcd * npx + (rr % npx);
  int bm = rr / npx;

  const size_t astride = ATILE;
  const size_t bstride = (size_t)N * 32;
  const bf16* Abase = A + (size_t)bm * TM * 32 + (size_t)lane * 8;
  const bf16* Bbase = Bt + (size_t)bn * TN * 32 + (size_t)lane * 8;

  f32x4 acc[MT][NT] = {};
  const int KT = K >> 5;

  auto stage = [&](int buf, int kt) {
    const bf16* Ab = Abase + (size_t)kt * astride;
    const bf16* Bb = Bbase + (size_t)kt * bstride;
#pragma unroll
    for (int i = 0; i < MT / 2; i++)
      g2l16(Ab + (wave + 4 * i) * 512, &As[buf][(wave + 4 * i) * 512]);
#pragma unroll
    for (int i = 0; i < NT / 2; i++)
      g2l16(Bb + (wave + 4 * i) * 512, &Bs[buf][(wave + 4 * i) * 512]);
  };

  stage(0, 0);
  int buf = 0;
  for (int kt = 0; kt < KT; kt++) {
    __syncthreads();
    if (kt + 1 < KT) stage(buf ^ 1, kt + 1);
    bf16x8 af[MT], bfr[NT];
#pragma unroll
    for (int mt = 0; mt < MT; mt++)
      af[mt] = *(const bf16x8*)&As[buf][(wm * MT * 16 + mt * 16 + l16) * 32 + quad * 8];
#pragma unroll
    for (int nt = 0; nt < NT; nt++)
      bfr[nt] = *(const bf16x8*)&Bs[buf][(wn * NT * 16 + nt * 16 + l16) * 32 + quad * 8];
#pragma unroll
    for (int mt = 0; mt < MT; mt++)
#pragma unroll
      for (int nt = 0; nt < NT; nt++)
        acc[mt][nt] = __builtin_amdgcn_mfma_f32_16x16x32_bf16(af[mt], bfr[nt], acc[mt][nt], 0, 0, 0);
    buf ^= 1;
  }

#pragma unroll
  for (int mt = 0; mt < MT; mt++) {
#pragma unroll
    for (int nt = 0; nt < NT; nt++) {
      int row0 = bm * TM + wm * MT * 16 + mt * 16 + quad * 4;
      int col = bn * TN + wn * NT * 16 + nt * 16 + l16;
      if (EPI == 0) {
        int b = row0 >> 11, l = row0 & 2047;
        int which = col >> 10, d = col & 1023;
        int hh = d >> 6, hdi = d & 63;
        size_t bh = (size_t)(b * 16 + hh);
        if (which == 0) {
#pragma unroll
          for (int r = 0; r < 4; r++)
            ob0[(bh * 2048 + l + r) * 64 + hdi] = (bf16)(acc[mt][nt][r] * QSCALE);
        } else if (which == 1) {
#pragma unroll
          for (int r = 0; r < 4; r++)
            ob1[(bh * 2048 + l + r) * 64 + hdi] = (bf16)acc[mt][nt][r];
        } else {
          short4v v4;
#pragma unroll
          for (int r = 0; r < 4; r++) v4[r] = f2bf(acc[mt][nt][r]);
          *(short4v*)&ob2[(bh * 64 + hdi) * 2048 + l] = v4;
        }
      } else {
#pragma unroll
        for (int r = 0; r < 4; r++) {
          int row = row0 + r;
          float v = acc[mt][nt][r];
          if (EPI == 1) {
            size_t idx = (size_t)row * N + col;
            outf[idx] = v + bias[col] + resid[idx];
          } else {
            float t = v + bias[col];
            float a = 0.7978845608028654f * t * (1.f + 0.044715f * t * t);
            float g = 0.5f * t * (1.f + fast_tanh(a));
            ob0[(size_t)(col >> 5) * ATILE + (size_t)row * 32 + (col & 31)] = (bf16)g;
          }
        }
      }
    }
  }
}

// ---------------- flash attention v10 ----------------
// v9 + (a) register-prefetch staging: global loads for kt+1 issue right
// after the post-staging barrier and complete under the compute phase;
// between barriers only LDS writes remain. (b) deferred lrow reduction
// (lane-local partials, one shuffle-reduce at the end). (c) packed bf16
// converts.
__global__ __launch_bounds__(256, 2) void flash_attn(
    const bf16* __restrict__ Q, const bf16* __restrict__ Kg,
    const bf16* __restrict__ Vg, bf16* __restrict__ O)
{
  __shared__ __align__(16) bf16 Ks[128 * 72];   // [kpos][hd], padded
  __shared__ __align__(16) bf16 Vs[64 * 136];   // [hd][kpos], padded
  const int tid = threadIdx.x, lane = tid & 63, wave = tid >> 6;
  const int quad = lane >> 4, l16 = lane & 15;
  const int qt = blockIdx.x, bh = blockIdx.y;
  const int b = bh >> 4, h = bh & 15;

  const bf16* qg = Q + ((size_t)bh * 2048 + qt * 128) * 64;
  const bf16* kg = Kg + (size_t)bh * 2048 * 64;
  const bf16* vg = Vg + (size_t)bh * 64 * 2048;

  bf16x8 qf[2][2];
#pragma unroll
  for (int s = 0; s < 2; s++)
#pragma unroll
    for (int kk = 0; kk < 2; kk++)
      qf[s][kk] = *(const bf16x8*)&qg[(size_t)(wave * 32 + s * 16 + l16) * 64 + kk * 32 + quad * 8];

  f32x4 oacc[2][4] = {};
  float lrow[2] = {0.f, 0.f};   // lane-local partials; reduced once at end

  // register prefetch of kt=0
  bf16x8 kreg[4], vreg[4];
#pragma unroll
  for (int i = 0; i < 4; i++) {
    int t = tid + i * 256;
    kreg[i] = *(const bf16x8*)&kg[(size_t)(t >> 3) * 64 + (t & 7) * 8];
    vreg[i] = *(const bf16x8*)&vg[(size_t)(t >> 4) * 2048 + (t & 15) * 8];
  }

  for (int kt = 0; kt < 16; kt++) {
    __syncthreads();                    // previous compute done -> LDS free
#pragma unroll
    for (int i = 0; i < 4; i++) {
      int t = tid + i * 256;
      *(bf16x8*)&Ks[(t >> 3) * 72 + (t & 7) * 8] = kreg[i];
      *(bf16x8*)&Vs[(t >> 4) * 136 + (t & 15) * 8] = vreg[i];
    }
    __syncthreads();
    if (kt < 15) {                      // loads covered by compute below
#pragma unroll
      for (int i = 0; i < 4; i++) {
        int t = tid + i * 256;
        kreg[i] = *(const bf16x8*)&kg[((size_t)(kt + 1) * 128 + (t >> 3)) * 64 + (t & 7) * 8];
        vreg[i] = *(const bf16x8*)&vg[(size_t)(t >> 4) * 2048 + (kt + 1) * 128 + (t & 15) * 8];
      }
    }

    // S^T = K.Q^T : 8 kpos-tiles x 2 q-subtiles, K-dim 64 = 2 chunks
    f32x4 sacc[2][8] = {};
#pragma unroll
    for (int kk = 0; kk < 2; kk++) {
#pragma unroll
      for (int ct = 0; ct < 8; ct++) {
        bf16x8 kf = *(const bf16x8*)&Ks[(ct * 16 + l16) * 72 + kk * 32 + quad * 8];
        sacc[0][ct] = __builtin_amdgcn_mfma_f32_16x16x32_bf16(kf, qf[0][kk], sacc[0][ct], 0, 0, 0);
        sacc[1][ct] = __builtin_amdgcn_mfma_f32_16x16x32_bf16(kf, qf[1][kk], sacc[1][ct], 0, 0, 0);
      }
    }

    // no-max softmax (exp2 domain), packed bf16 converts
    short4v pf[2][8];
#pragma unroll
    for (int s = 0; s < 2; s++) {
      float sum = 0.f;
#pragma unroll
      for (int ct = 0; ct < 8; ct++) {
        float p0 = fast_exp2(sacc[s][ct][0]);
        float p1 = fast_exp2(sacc[s][ct][1]);
        float p2 = fast_exp2(sacc[s][ct][2]);
        float p3 = fast_exp2(sacc[s][ct][3]);
        sum += (p0 + p1) + (p2 + p3);
        uint2v u;
        u[0] = pk_bf16(p0, p1);
        u[1] = pk_bf16(p2, p3);
        pf[s][ct] = __builtin_bit_cast(short4v, u);
      }
      lrow[s] += sum;
    }

    // O^T += V^T . P^T  (A = V^T frag from LDS, B = P^T frag in registers)
#pragma unroll
    for (int ot = 0; ot < 4; ot++) {
#pragma unroll
      for (int ct = 0; ct < 8; ct++) {
        short4v vf = *(const short4v*)&Vs[(ot * 16 + l16) * 136 + ct * 16 + quad * 4];
        oacc[0][ot] = __builtin_amdgcn_mfma_f32_16x16x16bf16_1k(vf, pf[0][ct], oacc[0][ot], 0, 0, 0);
        oacc[1][ot] = __builtin_amdgcn_mfma_f32_16x16x16bf16_1k(vf, pf[1][ct], oacc[1][ot], 0, 0, 0);
      }
    }
  }

  // epilogue: finish lrow reduce (quads hold disjoint kpos partials), store
#pragma unroll
  for (int s = 0; s < 2; s++) {
    float l = lrow[s];
    l += __shfl_xor(l, 16);
    l += __shfl_xor(l, 32);
    float inv = 1.f / l;
    int qrow = qt * 128 + wave * 32 + s * 16 + l16;
    size_t grow = (size_t)b * 2048 + qrow;
#pragma unroll
    for (int ot = 0; ot < 4; ot++) {
      int col = h * 64 + ot * 16 + quad * 4;
      short4v o4;
#pragma unroll
      for (int r = 0; r < 4; r++) o4[r] = f2bf(oacc[s][ot][r] * inv);
      *(short4v*)&O[(size_t)(col >> 5) * ATILE + grow * 32 + (col & 31)] = o4;
    }
  }
}

// ---------------- launch ----------------
extern "C" void kernel_launch(void* const* d_in, const int* in_sizes, int n_in,
                              void* d_out, int out_size, void* d_ws, size_t ws_size,
                              hipStream_t stream)
{
  const float* x     = (const float*)d_in[0];
  const float* ln1s  = (const float*)d_in[1];
  const float* ln1b  = (const float*)d_in[2];
  const float* wqkv  = (const float*)d_in[3];
  const float* wproj = (const float*)d_in[4];
  const float* bproj = (const float*)d_in[5];
  const float* ln2s  = (const float*)d_in[6];
  const float* ln2b  = (const float*)d_in[7];
  const float* wmlp1 = (const float*)d_in[8];
  const float* bmlp1 = (const float*)d_in[9];
  const float* wmlp2 = (const float*)d_in[10];
  const float* bmlp2 = (const float*)d_in[11];
  float* out = (float*)d_out;

  char* ws = (char*)d_ws;
  bf16* wqkv_t  = (bf16*)(ws + 0);          // tiled [32][3072][32]
  bf16* wproj_t = (bf16*)(ws + 6291456);    // tiled [32][1024][32]
  bf16* wmlp1_t = (bf16*)(ws + 8388608);    // tiled [32][4096][32]
  bf16* wmlp2_t = (bf16*)(ws + 16777216);   // tiled [128][1024][32]
  bf16* hbuf    = (bf16*)(ws + 25165824);   // tiled [32][4096][32]
  bf16* qb      = (bf16*)(ws + 33554432);   // [32,2048,64]
  bf16* kb      = (bf16*)(ws + 41943040);   // [32,2048,64]
  bf16* vb      = (bf16*)(ws + 50331648);   // [32,64,2048]
  bf16* aout    = (bf16*)(ws + 58720256);   // tiled [32][4096][32]
  bf16* mbuf    = (bf16*)(ws + 33554432);   // tiled [128][4096][32] aliases q/k/v/aout

  prep_kernel<<<16384, 256, 0, stream>>>(wqkv, wproj, wmlp1, wmlp2,
                                         wqkv_t, wproj_t, wmlp1_t, wmlp2_t,
                                         x, ln1s, ln1b, hbuf);
  gemm_tt<4, 4, 0><<<dim3(24, 32), 256, 0, stream>>>(hbuf, wqkv_t, 3072, 1024,
                                                     nullptr, nullptr, nullptr, qb, kb, vb);
  flash_attn<<<dim3(16, 32), 256, 0, stream>>>(qb, kb, vb, aout);
  gemm_tt<2, 4, 1><<<dim3(8, 64), 256, 0, stream>>>(aout, wproj_t, 1024, 1024,
                                                    bproj, x, out, nullptr, nullptr, nullptr);
  ln_kernel<<<4096, 256, 0, stream>>>(out, ln2s, ln2b, hbuf);
  gemm_tt<4, 4, 2><<<dim3(32, 32), 256, 0, stream>>>(hbuf, wmlp1_t, 4096, 1024,
                                                     bmlp1, nullptr, nullptr, mbuf, nullptr, nullptr);
  gemm_tt<2, 4, 1><<<dim3(8, 64), 256, 0, stream>>>(mbuf, wmlp2_t, 1024, 4096,
                                                    bmlp2, out, out, nullptr, nullptr, nullptr);
}